// Round 1
// baseline (30.372 us; speedup 1.0000x reference)
//
#include <hip/hip_runtime.h>

// CenterWeightedCIoULoss: mean over N matched pairs of
//   (1 - IoU) + 2 * center_dist^2/(c_diag^2+eps+eps) + size_term
// Memory-bound streaming reduction: 128 MiB in, 4 B out.

#define EPSF 1e-7f

__device__ __forceinline__ float wave_block_reduce(float acc, float* lds_ws) {
    // wave (64-lane) butterfly via shfl_down, then cross-wave via LDS.
    #pragma unroll
    for (int off = 32; off > 0; off >>= 1)
        acc += __shfl_down(acc, off, 64);
    const int lane = threadIdx.x & 63;
    const int wave = threadIdx.x >> 6;
    if (lane == 0) lds_ws[wave] = acc;
    __syncthreads();
    float s = 0.f;
    if (threadIdx.x == 0) {
        const int nwaves = blockDim.x >> 6;
        for (int w = 0; w < nwaves; ++w) s += lds_ws[w];
    }
    return s;  // valid in thread 0 only
}

__global__ void ciou_partial_kernel(const float4* __restrict__ pred,
                                    const float4* __restrict__ targ,
                                    float* __restrict__ partial, int n) {
    const int tid = blockIdx.x * blockDim.x + threadIdx.x;
    const int stride = gridDim.x * blockDim.x;
    float acc = 0.f;
    for (int i = tid; i < n; i += stride) {
        const float4 p = pred[i];
        const float4 t = targ[i];
        const float px1 = p.x, py1 = p.y, px2 = p.z, py2 = p.w;
        const float tx1 = t.x, ty1 = t.y, tx2 = t.z, ty2 = t.w;

        // IoU
        float iw = fminf(px2, tx2) - fmaxf(px1, tx1);
        float ih = fminf(py2, ty2) - fmaxf(py1, ty1);
        iw = fmaxf(iw, 0.f);
        ih = fmaxf(ih, 0.f);
        const float inter  = iw * ih;
        const float pw = px2 - px1, ph = py2 - py1;
        const float tw = tx2 - tx1, th = ty2 - ty1;
        const float p_area = pw * ph;
        const float t_area = tw * th;
        const float iou = inter / (p_area + t_area - inter + EPSF);

        // center term (note: eps is added twice, faithful to reference)
        const float dcx = 0.5f * ((px1 + px2) - (tx1 + tx2));
        const float dcy = 0.5f * ((py1 + py2) - (ty1 + ty2));
        const float center_dist_sq = dcx * dcx + dcy * dcy;
        const float cw = fmaxf(px2, tx2) - fminf(px1, tx1);
        const float ch = fmaxf(py2, ty2) - fminf(py1, ty1);
        const float c_diag_sq = cw * cw + ch * ch + EPSF;
        const float center_term = center_dist_sq / (c_diag_sq + EPSF);

        // size term
        const float sw = (pw - tw) / (tw + EPSF);
        const float sh = (ph - th) / (th + EPSF);
        const float size_term = sw * sw + sh * sh;

        acc += (1.f - iou) + 2.f * center_term + size_term;
    }

    __shared__ float lds_ws[8];
    const float blk = wave_block_reduce(acc, lds_ws);
    if (threadIdx.x == 0) partial[blockIdx.x] = blk;
}

__global__ void ciou_final_kernel(const float* __restrict__ partial, int nparts,
                                  float* __restrict__ out, float inv_n) {
    float acc = 0.f;
    for (int i = threadIdx.x; i < nparts; i += blockDim.x)
        acc += partial[i];
    __shared__ float lds_ws[8];
    const float s = wave_block_reduce(acc, lds_ws);
    if (threadIdx.x == 0) out[0] = s * inv_n;
}

extern "C" void kernel_launch(void* const* d_in, const int* in_sizes, int n_in,
                              void* d_out, int out_size, void* d_ws, size_t ws_size,
                              hipStream_t stream) {
    const float4* pred = (const float4*)d_in[0];
    const float4* targ = (const float4*)d_in[1];
    float* out = (float*)d_out;
    float* partial = (float*)d_ws;

    const int n = in_sizes[0] / 4;  // number of boxes
    const int block = 256;
    const int grid = 2048;          // grid-stride; ~8 elems/thread at N=4M

    ciou_partial_kernel<<<grid, block, 0, stream>>>(pred, targ, partial, n);
    ciou_final_kernel<<<1, block, 0, stream>>>(partial, grid, out, 1.0f / (float)n);
}